// Round 14
// baseline (409.363 us; speedup 1.0000x reference)
//
#include <hip/hip_runtime.h>
#include <cstddef>

constexpr int N0 = 16384, N1 = 4096, N2 = 1024, N3 = 256;
constexpr int E0 = 6 * N0, E1 = 6 * N1, E2 = 6 * N2, E3 = 6 * N3;
constexpr int ETOT = E0 + E1 + E2 + E3; // 129024
constexpr int LOCN = 32 * N0;           // 524288

// ---- workspace layout (4-byte units) ----
constexpr size_t O_CNT  = 0;        // 21760 ints
constexpr size_t O_STAT = 21760;    // 384 floats (zeroed with cnt)
constexpr size_t O_BK   = 22144;    // buckets: A0@0, A1@524288, A2@655360, A3@688128
constexpr size_t O_YL0  = 720896;
constexpr size_t O_XL1  = O_YL0 + 524288;
constexpr size_t O_YL1  = O_XL1 + 524288;
constexpr size_t O_XL2  = O_YL1 + 524288;
constexpr size_t O_YL2  = O_XL2 + 524288;
constexpr size_t O_XL3  = O_YL2 + 524288;
constexpr size_t O_YL3  = O_XL3 + 524288;  // 49152
constexpr size_t O_YG0  = O_YL3 + 49152;   // 8192
constexpr size_t O_XG1  = O_YG0 + 8192;
constexpr size_t O_XWG1 = O_XG1 + 8192;
constexpr size_t O_YG1  = O_XWG1 + 8192;   // 32768
constexpr size_t O_XG2  = O_YG1 + 32768;
constexpr size_t O_XWG2 = O_XG2 + 32768;
constexpr size_t O_YG2  = O_XWG2 + 32768;  // 131072
constexpr size_t O_XG3  = O_YG2 + 131072;
constexpr size_t O_XW3  = O_XG3 + 131072;  // 12288
constexpr size_t O_YG3  = O_XW3 + 12288;   // 49152
constexpr size_t O_XLZ  = O_YG3 + 49152;   // 128

struct Params {
    const float *z, *lin_w, *lin_b, *loc_w, *loc_b, *Wg, *bg, *Wg3, *bg3;
    const float *Wl, *bl, *Wl3, *bl3, *gam_g, *bet_g, *gam_l, *bet_l;
    const float *U0, *U1, *U2, *U3;
    const int *A0, *A1, *A2, *A3;
    float* ws;
    float* out;
};

// ============ bucket-CSR fill (one pass, all 4 graphs) ============
__device__ void fill_edges(const Params& P, int rb, int nrb) {
    int* cnt = (int*)(P.ws + O_CNT);
    int* bk  = (int*)(P.ws + O_BK);
    for (int e = rb * 256 + threadIdx.x; e < ETOT; e += nrb * 256) {
        const int* A; int E, co, bo; int x = e;
        if (x < E0)              { A = P.A0; E = E0; co = 0;     bo = 0; }
        else if ((x -= E0) < E1) { A = P.A1; E = E1; co = 16384; bo = 524288; }
        else if ((x -= E1) < E2) { A = P.A2; E = E2; co = 20480; bo = 655360; }
        else { x -= E2;            A = P.A3; E = E3; co = 21504; bo = 688128; }
        int s = A[x], d = A[E + x];
        int slot = atomicAdd(cnt + co + d, 1);
        if (slot < 32) bk[bo + d * 32 + slot] = s;
    }
}

// ============ fused matvec + @Wl0 chunk ============
template <bool SELF_XLZ>
__device__ void matvec_y(const Params& P, int mb, float* sm) {
    float* xs   = sm;          // 128
    float* xrow = sm + 128;    // 1024
    float* Wl   = sm + 1152;   // 1024
    float* zl   = sm + 2176;   // 128
    int t = threadIdx.x;
    for (int i = t; i < 1024; i += 256) Wl[i] = P.Wl[i];
    if (SELF_XLZ) {
        if (t < 128) zl[t] = P.z[t];
        __syncthreads();
        if (t < 128) {
            float s = P.lin_b[32 + t];
#pragma unroll 8
            for (int k = 0; k < 128; k++) s += zl[k] * P.lin_w[k * 160 + 32 + t];
            xs[t] = s;
        }
    } else {
        if (t < 128) xs[t] = (P.ws + O_XLZ)[t];
    }
    __syncthreads();
    size_t j0 = (size_t)mb * 1024 + t * 4;
    float4 acc = *(const float4*)(P.loc_b + j0);
#pragma unroll 8
    for (int k = 0; k < 128; k++) {
        float xk = xs[k];
        float4 w = *(const float4*)(P.loc_w + (size_t)k * LOCN + j0);
        acc.x += xk * w.x; acc.y += xk * w.y; acc.z += xk * w.z; acc.w += xk * w.w;
    }
    *(float4*)(xrow + t * 4) = acc;
    __syncthreads();
    float* yl0 = P.ws + O_YL0;
#pragma unroll
    for (int q = 0; q < 4; q++) {
        int idx = q * 256 + t;
        int nn = idx >> 5, f = idx & 31;
        float s = 0.f;
        const float* xr = xrow + nn * 32;
#pragma unroll
        for (int k = 0; k < 32; k++) s += xr[k] * Wl[k * 32 + f];
        yl0[(size_t)mb * 1024 + idx] = s;
    }
}

// ============ lin head: xlz->ws, rank-1 U3 level -> YG0 ============
__device__ void lin_u3(const Params& P, float* sm) {
    float* zl  = sm;
    float* xl  = sm + 128;
    float* xw0 = sm + 288;
    int t = threadIdx.x;
    if (t < 128) zl[t] = P.z[t];
    __syncthreads();
    if (t < 160) {
        float s = P.lin_b[t];
        for (int k = 0; k < 128; k++) s += zl[k] * P.lin_w[k * 160 + t];
        xl[t] = s;
    }
    __syncthreads();
    if (t < 128) (P.ws + O_XLZ)[t] = xl[32 + t];
    if (t < 32) {
        float s = 0.f;
        for (int k = 0; k < 32; k++) s += xl[k] * P.Wg[k * 32 + t];
        xw0[t] = s;
    }
    __syncthreads();
    float rs = 0.f;
    for (int k = 0; k < 64; k++) rs += P.U3[t * 64 + k];
    float* y = P.ws + O_YG0;
    for (int f = 0; f < 32; f++) y[t * 32 + f] = rs * xw0[f];
}

// ============ bucket gather (F=32) + bias + BN stats ============
template <int WPB>
__device__ void gatherB(const int* cnt, const int* bk, const float* y,
                        const float* bias, int n, float* xout, float* stats,
                        int rb, int nrb, float* sm) {
    int t = threadIdx.x, f = t & 31, half = (t >> 5) & 1, w = t >> 6;
    float bf = bias[f];
    float s = 0.f, ss = 0.f;
    for (int node = rb * WPB + w; node < n; node += nrb * WPB) {
        int c = cnt[node];
        int cl = c < 32 ? c : 32;
        const int* b = bk + (size_t)node * 32;
        float a = half ? 0.f : y[(size_t)node * 32 + f];
        for (int r = half; r < cl; r += 2)
            a += y[(size_t)b[r] * 32 + f];
        a += __shfl_down(a, 32, 64);
        if (!half) {
            float v = a / (float)(c + 1) + bf;
            xout[(size_t)node * 32 + f] = v;
            s += v; ss += v * v;
        }
    }
    if (t < 64) sm[t] = 0.f;
    __syncthreads();
    if (!half) { atomicAdd(sm + f, s); atomicAdd(sm + 32 + f, ss); }
    __syncthreads();
    if (t < 64) atomicAdd(stats + t, sm[t]);
}

// ============ BN + leakyReLU + row @ W(32xFO), 512 threads ============
template <int FO>
__device__ void bnxw512(const float* xin, const float* stats, const float* gam,
                        const float* bet, const float* W, float invn, int n,
                        float* out, int rb, float* sm) {
    float* Wl = sm;
    float* sc = sm + 32 * FO;
    float* sh = sc + 32;
    int t = threadIdx.x;
    for (int i = t; i < 32 * FO; i += 512) Wl[i] = W[i];
    if (t < 32) {
        float mu = stats[t] * invn;
        float var = stats[32 + t] * invn - mu * mu;
        float rs = rsqrtf(var + 1e-5f);
        float scv = rs * gam[t];
        sc[t] = scv; sh[t] = bet[t] - mu * scv;
    }
    __syncthreads();
    int node = rb * 512 + t;
    if (node < n) {
        float x[32];
        const float4* xp = (const float4*)(xin + (size_t)node * 32);
#pragma unroll
        for (int j = 0; j < 8; j++) {
            float4 v = xp[j];
            x[4 * j] = v.x; x[4 * j + 1] = v.y; x[4 * j + 2] = v.z; x[4 * j + 3] = v.w;
        }
#pragma unroll
        for (int k = 0; k < 32; k++) {
            float v = sc[k] * x[k] + sh[k];
            x[k] = v > 0.f ? v : 0.01f * v;
        }
        float yv[FO];
#pragma unroll
        for (int q = 0; q < FO; q++) {
            float s = 0.f;
#pragma unroll
            for (int k = 0; k < 32; k++) s += x[k] * Wl[k * FO + q];
            yv[q] = s;
        }
        float* yp = out + (size_t)node * FO;
#pragma unroll
        for (int q = 0; q < FO; q++) yp[q] = yv[q];
    }
}

// 256-thread bn_g0 (one block, n=256)
__device__ void bnxw256_g0(const Params& P, float* sm) {
    float* ws = P.ws;
    const float* stats = ws + O_STAT;
    float* Wl = sm;
    float* sc = sm + 1024;
    float* sh = sc + 32;
    int t = threadIdx.x;
    for (int i = t; i < 1024; i += 256) Wl[i] = P.Wg[1024 + i];
    if (t < 32) {
        float invn = 1.f / N3;
        float mu = stats[t] * invn;
        float var = stats[32 + t] * invn - mu * mu;
        float rs = rsqrtf(var + 1e-5f);
        float scv = rs * P.gam_g[t];
        sc[t] = scv; sh[t] = P.bet_g[t] - mu * scv;
    }
    __syncthreads();
    const float* xin = ws + O_XG1;
    float x[32];
    const float4* xp = (const float4*)(xin + (size_t)t * 32);
#pragma unroll
    for (int j = 0; j < 8; j++) {
        float4 v = xp[j];
        x[4 * j] = v.x; x[4 * j + 1] = v.y; x[4 * j + 2] = v.z; x[4 * j + 3] = v.w;
    }
#pragma unroll
    for (int k = 0; k < 32; k++) {
        float v = sc[k] * x[k] + sh[k];
        x[k] = v > 0.f ? v : 0.01f * v;
    }
    float* yp = ws + O_XWG1 + (size_t)t * 32;
#pragma unroll
    for (int q = 0; q < 32; q++) {
        float s = 0.f;
#pragma unroll
        for (int k = 0; k < 32; k++) s += x[k] * Wl[k * 32 + q];
        yp[q] = s;
    }
}

// ============ y = U(64 rows) @ xw(m x 32), 512 threads ============
__device__ void gemm512(const float* U, const float* xw, int m, float* y,
                        int rb, float* sm) {
    float* ut = sm;          // 64*64
    float* xt = sm + 4096;   // 64*32
    int t = threadIdx.x, f = t & 31, rg = t >> 5;
    int r0 = rb * 64;
    float a0 = 0, a1 = 0, a2 = 0, a3 = 0;
    for (int k0 = 0; k0 < m; k0 += 64) {
        {
            int row = t >> 3, c0 = (t & 7) * 8;
            const float* src = U + (size_t)(r0 + row) * m + k0 + c0;
            *(float4*)(ut + row * 64 + c0) = *(const float4*)src;
            *(float4*)(ut + row * 64 + c0 + 4) = *(const float4*)(src + 4);
        }
        {
            int kk = t >> 3, c0 = (t & 7) * 4;
            *(float4*)(xt + kk * 32 + c0) =
                *(const float4*)(xw + (size_t)(k0 + kk) * 32 + c0);
        }
        __syncthreads();
#pragma unroll
        for (int kk = 0; kk < 64; kk++) {
            float xv = xt[kk * 32 + f];
            a0 += ut[rg * 64 + kk] * xv;
            a1 += ut[(rg + 16) * 64 + kk] * xv;
            a2 += ut[(rg + 32) * 64 + kk] * xv;
            a3 += ut[(rg + 48) * 64 + kk] * xv;
        }
        __syncthreads();
    }
    y[(size_t)(r0 + rg) * 32 + f] = a0;
    y[(size_t)(r0 + rg + 16) * 32 + f] = a1;
    y[(size_t)(r0 + rg + 32) * 32 + f] = a2;
    y[(size_t)(r0 + rg + 48) * 32 + f] = a3;
}

// ================= D1: mv[0:191) | bucket-fill | lin+U3  (256) ============
__global__ void __launch_bounds__(256) k_d1(Params P) {
    __shared__ float sm[2304];
    int bid = blockIdx.x;
    if (bid < 191)      matvec_y<true>(P, bid, sm);
    else if (bid < 255) fill_edges(P, bid - 191, 64);
    else                lin_u3(P, sm);
}

// ================= D2: mv[191:443) | g_g0(A3)  (256) ============
__global__ void __launch_bounds__(256) k_d2(Params P) {
    __shared__ float sm[2304];
    int bid = blockIdx.x;
    float* ws = P.ws;
    if (bid < 252) {
        matvec_y<false>(P, 191 + bid, sm);
    } else {
        const int* cnt = (int*)(ws + O_CNT);
        const int* bk  = (int*)(ws + O_BK);
        gatherB<4>(cnt + 21504, bk + 688128, ws + O_YG0, P.bg, N3,
                   ws + O_XG1, ws + O_STAT, bid - 252, 4, sm);
    }
}

// ================= D3: mv[443:512) | bn_g0  (70) ============
__global__ void __launch_bounds__(256) k_d3(Params P) {
    __shared__ float sm[2304];
    int bid = blockIdx.x;
    if (bid < 69) matvec_y<false>(P, 443 + bid, sm);
    else          bnxw256_g0(P, sm);
}

// ================= D4: g_l0 | gemmU2  (256 x 512) ============
__global__ void __launch_bounds__(512) k_d4(Params P) {
    __shared__ float sm[6144];
    int bid = blockIdx.x;
    float* ws = P.ws;
    const int* cnt = (int*)(ws + O_CNT);
    const int* bk  = (int*)(ws + O_BK);
    if (bid < 240)
        gatherB<8>(cnt, bk, ws + O_YL0, P.bl, N0, ws + O_XL1,
                   ws + O_STAT + 192, bid, 240, sm);
    else
        gemm512(P.U2, ws + O_XWG1, 256, ws + O_YG1, bid - 240, sm);
}

// ================= D5: bn_l0 | g_g1(A2)  (48 x 512) ============
__global__ void __launch_bounds__(512) k_d5(Params P) {
    __shared__ float sm[1152];
    int bid = blockIdx.x;
    float* ws = P.ws;
    const int* cnt = (int*)(ws + O_CNT);
    const int* bk  = (int*)(ws + O_BK);
    if (bid < 32)
        bnxw512<32>(ws + O_XL1, ws + O_STAT + 192, P.gam_l, P.bet_l, P.Wl + 1024,
                    1.f / N0, N0, ws + O_YL1, bid, sm);
    else
        gatherB<8>(cnt + 20480, bk + 655360, ws + O_YG1, P.bg + 32, N2,
                   ws + O_XG2, ws + O_STAT + 64, bid - 32, 16, sm);
}

// ================= D6: g_l1 | bn_g1  (242 x 512) ============
__global__ void __launch_bounds__(512) k_d6(Params P) {
    __shared__ float sm[1152];
    int bid = blockIdx.x;
    float* ws = P.ws;
    const int* cnt = (int*)(ws + O_CNT);
    const int* bk  = (int*)(ws + O_BK);
    if (bid < 240)
        gatherB<8>(cnt, bk, ws + O_YL1, P.bl + 32, N0, ws + O_XL2,
                   ws + O_STAT + 256, bid, 240, sm);
    else
        bnxw512<32>(ws + O_XG2, ws + O_STAT + 64, P.gam_g + 32, P.bet_g + 32,
                    P.Wg + 2048, 1.f / N2, N2, ws + O_XWG2, bid - 240, sm);
}

// ================= D7: bn_l1 | gemmU1  (96 x 512) ============
__global__ void __launch_bounds__(512) k_d7(Params P) {
    __shared__ float sm[6144];
    int bid = blockIdx.x;
    float* ws = P.ws;
    if (bid < 32)
        bnxw512<32>(ws + O_XL2, ws + O_STAT + 256, P.gam_l + 32, P.bet_l + 32,
                    P.Wl + 2048, 1.f / N0, N0, ws + O_YL2, bid, sm);
    else
        gemm512(P.U1, ws + O_XWG2, 1024, ws + O_YG2, bid - 32, sm);
}

// ================= D8: g_l2 | g_g2(A1)  (256 x 512) ============
__global__ void __launch_bounds__(512) k_d8(Params P) {
    __shared__ float sm[64];
    int bid = blockIdx.x;
    float* ws = P.ws;
    const int* cnt = (int*)(ws + O_CNT);
    const int* bk  = (int*)(ws + O_BK);
    if (bid < 240)
        gatherB<8>(cnt, bk, ws + O_YL2, P.bl + 64, N0, ws + O_XL3,
                   ws + O_STAT + 320, bid, 240, sm);
    else
        gatherB<8>(cnt + 16384, bk + 524288, ws + O_YG2, P.bg + 64, N1,
                   ws + O_XG3, ws + O_STAT + 128, bid - 240, 16, sm);
}

// ================= D9: bn_l2 (FO=3) | bn_g2 (FO=3)  (40 x 512) ============
__global__ void __launch_bounds__(512) k_d9(Params P) {
    __shared__ float sm[256];
    int bid = blockIdx.x;
    float* ws = P.ws;
    if (bid < 32)
        bnxw512<3>(ws + O_XL3, ws + O_STAT + 320, P.gam_l + 64, P.bet_l + 64,
                   P.Wl3, 1.f / N0, N0, ws + O_YL3, bid, sm);
    else
        bnxw512<3>(ws + O_XG3, ws + O_STAT + 128, P.gam_g + 64, P.bet_g + 64,
                   P.Wg3, 1.f / N1, N1, ws + O_XW3, bid - 32, sm);
}

// ===== D10: yg3 = U0 @ xw3 — 512 thr, 8 waves, 4-row groups, LDS reuse =====
__global__ void __launch_bounds__(512) k_d10(Params P) {
    __shared__ float pl[12288];
    int t = threadIdx.x;
    const float* xw3 = P.ws + O_XW3;
    float* y = P.ws + O_YG3;
    for (int i = t; i < 12288; i += 512) {
        int k = i / 3, h = i - 3 * k;
        pl[h * 4096 + ((k & 3) << 10) + (k >> 2)] = xw3[i];
    }
    __syncthreads();
    int w = t >> 6, lane = t & 63;
    // 256 blocks x 64 rows: each wave does 2 groups of 4 consecutive rows.
    for (int g = 0; g < 2; g++) {
        int row0 = blockIdx.x * 64 + w * 8 + g * 4;
        const float4* up0 = (const float4*)(P.U0 + (size_t)row0 * 4096);
        const float4* up1 = (const float4*)(P.U0 + (size_t)(row0 + 1) * 4096);
        const float4* up2 = (const float4*)(P.U0 + (size_t)(row0 + 2) * 4096);
        const float4* up3 = (const float4*)(P.U0 + (size_t)(row0 + 3) * 4096);
        float a[4][3];
#pragma unroll
        for (int r = 0; r < 4; r++) { a[r][0] = 0.f; a[r][1] = 0.f; a[r][2] = 0.f; }
#pragma unroll 4
        for (int c = 0; c < 16; c++) {
            int b = c * 64 + lane;
            float4 u0 = up0[b], u1 = up1[b], u2 = up2[b], u3 = up3[b];
            float p00 = pl[b],         p01 = pl[1024 + b],  p02 = pl[2048 + b],  p03 = pl[3072 + b];
            float p10 = pl[4096 + b],  p11 = pl[5120 + b],  p12 = pl[6144 + b],  p13 = pl[7168 + b];
            float p20 = pl[8192 + b],  p21 = pl[9216 + b],  p22 = pl[10240 + b], p23 = pl[11264 + b];
            a[0][0] += u0.x * p00 + u0.y * p01 + u0.z * p02 + u0.w * p03;
            a[0][1] += u0.x * p10 + u0.y * p11 + u0.z * p12 + u0.w * p13;
            a[0][2] += u0.x * p20 + u0.y * p21 + u0.z * p22 + u0.w * p23;
            a[1][0] += u1.x * p00 + u1.y * p01 + u1.z * p02 + u1.w * p03;
            a[1][1] += u1.x * p10 + u1.y * p11 + u1.z * p12 + u1.w * p13;
            a[1][2] += u1.x * p20 + u1.y * p21 + u1.z * p22 + u1.w * p23;
            a[2][0] += u2.x * p00 + u2.y * p01 + u2.z * p02 + u2.w * p03;
            a[2][1] += u2.x * p10 + u2.y * p11 + u2.z * p12 + u2.w * p13;
            a[2][2] += u2.x * p20 + u2.y * p21 + u2.z * p22 + u2.w * p23;
            a[3][0] += u3.x * p00 + u3.y * p01 + u3.z * p02 + u3.w * p03;
            a[3][1] += u3.x * p10 + u3.y * p11 + u3.z * p12 + u3.w * p13;
            a[3][2] += u3.x * p20 + u3.y * p21 + u3.z * p22 + u3.w * p23;
        }
#pragma unroll
        for (int r = 0; r < 4; r++)
#pragma unroll
            for (int h = 0; h < 3; h++)
                for (int o = 32; o; o >>= 1)
                    a[r][h] += __shfl_down(a[r][h], o, 64);
        if (lane == 0) {
#pragma unroll
            for (int r = 0; r < 4; r++) {
                y[(row0 + r) * 3]     = a[r][0];
                y[(row0 + r) * 3 + 1] = a[r][1];
                y[(row0 + r) * 3 + 2] = a[r][2];
            }
        }
    }
}

// ================= D11: final combine over A0 buckets  (256 x 256) ============
__global__ void __launch_bounds__(256) k_d11(Params P) {
    int t = blockIdx.x * 256 + threadIdx.x;
    int node = t >> 2, r = t & 3;
    if (node >= N0 || r >= 3) return;
    float* ws = P.ws;
    const int* cnt = (int*)(ws + O_CNT);
    const int* bk  = (int*)(ws + O_BK);
    const float* yg = ws + O_YG3;
    const float* yl = ws + O_YL3;
    int c = cnt[node];
    int cl = c < 32 ? c : 32;
    const int* b = bk + (size_t)node * 32;
    float ag = yg[node * 3 + r], al = yl[node * 3 + r];
    for (int e = 0; e < cl; e++) {
        int s = b[e];
        ag += yg[s * 3 + r];
        al += yl[s * 3 + r];
    }
    float inv = 1.f / (float)(c + 1);
    P.out[node * 3 + r] = 0.01f * (ag * inv + P.bg3[r]) + 0.99f * (al * inv + P.bl3[r]);
}

extern "C" void kernel_launch(void* const* d_in, const int* in_sizes, int n_in,
                              void* d_out, int out_size, void* d_ws, size_t ws_size,
                              hipStream_t stream) {
    Params p;
    p.z     = (const float*)d_in[0];
    p.lin_w = (const float*)d_in[1];
    p.lin_b = (const float*)d_in[2];
    p.loc_w = (const float*)d_in[3];
    p.loc_b = (const float*)d_in[4];
    p.Wg    = (const float*)d_in[5];
    p.bg    = (const float*)d_in[8];
    p.Wg3   = (const float*)d_in[9];
    p.bg3   = (const float*)d_in[12];
    p.Wl    = (const float*)d_in[13];
    p.bl    = (const float*)d_in[16];
    p.Wl3   = (const float*)d_in[17];
    p.bl3   = (const float*)d_in[20];
    p.gam_g = (const float*)d_in[21];
    p.bet_g = (const float*)d_in[22];
    p.gam_l = (const float*)d_in[23];
    p.bet_l = (const float*)d_in[24];
    p.U0    = (const float*)d_in[25];
    p.U1    = (const float*)d_in[26];
    p.U2    = (const float*)d_in[27];
    p.U3    = (const float*)d_in[28];
    p.A0    = (const int*)d_in[29];
    p.A1    = (const int*)d_in[30];
    p.A2    = (const int*)d_in[31];
    p.A3    = (const int*)d_in[32];
    p.ws    = (float*)d_ws;
    p.out   = (float*)d_out;

    hipMemsetAsync(d_ws, 0, (21760 + 384) * 4, stream);  // cnt + stats
    k_d1 <<<256, 256, 0, stream>>>(p);
    k_d2 <<<256, 256, 0, stream>>>(p);
    k_d3 <<<70,  256, 0, stream>>>(p);
    k_d4 <<<256, 512, 0, stream>>>(p);
    k_d5 <<<48,  512, 0, stream>>>(p);
    k_d6 <<<242, 512, 0, stream>>>(p);
    k_d7 <<<96,  512, 0, stream>>>(p);
    k_d8 <<<256, 512, 0, stream>>>(p);
    k_d9 <<<40,  512, 0, stream>>>(p);
    k_d10<<<256, 512, 0, stream>>>(p);
    k_d11<<<256, 256, 0, stream>>>(p);
}

// Round 15
// 382.739 us; speedup vs baseline: 1.0696x; 1.0696x over previous
//
#include <hip/hip_runtime.h>
#include <cstddef>

constexpr int N0 = 16384, N1 = 4096, N2 = 1024, N3 = 256;
constexpr int E0 = 6 * N0, E1 = 6 * N1, E2 = 6 * N2, E3 = 6 * N3;
constexpr int ETOT = E0 + E1 + E2 + E3; // 129024
constexpr int LOCN = 32 * N0;           // 524288

// ---- workspace layout (4-byte units) ----
// deg + stats contiguous -> zeroed by ONE hipMemsetAsync
constexpr size_t O_DEG  = 0;          // 21760 int
constexpr size_t O_STAT = 21760;      // 384 f
constexpr size_t O_RP   = 22144;      // 21764 int
constexpr size_t O_CUR  = 43908;      // 21764 int
constexpr size_t O_EIDX = 65672;      // 130560 int
constexpr size_t O_XLZ  = 196232;     // 128
constexpr size_t O_XW0  = 196360;     // 2048 (64x32 broadcast)
constexpr size_t O_YG0  = 198408;     // 8192
constexpr size_t O_XG1  = 206600;
constexpr size_t O_XWG1 = 214792;
constexpr size_t O_YG1  = 222984;     // 32768
constexpr size_t O_XG2  = 255752;
constexpr size_t O_XWG2 = 288520;
constexpr size_t O_YG2  = 321288;     // 131072
constexpr size_t O_XG3  = 452360;
constexpr size_t O_XW3  = 583432;     // 12288
constexpr size_t O_YG3  = 595720;     // 49152
constexpr size_t O_YL0  = 644872;     // 524288
constexpr size_t O_XL1  = O_YL0 + 524288;
constexpr size_t O_YL1  = O_XL1 + 524288;
constexpr size_t O_XL2  = O_YL1 + 524288;
constexpr size_t O_YL2  = O_XL2 + 524288;
constexpr size_t O_XL3  = O_YL2 + 524288;
constexpr size_t O_YL3  = O_XL3 + 524288;  // 49152

struct Params {
    const float *z, *lin_w, *lin_b, *loc_w, *loc_b, *Wg, *bg, *Wg3, *bg3;
    const float *Wl, *bl, *Wl3, *bl3, *gam_g, *bet_g, *gam_l, *bet_l;
    const float *U0, *U1, *U2, *U3;
    const int *A0, *A1, *A2, *A3;
    float* ws;
    float* out;
};

// ============ fused matvec + @Wl0 chunk (R10 body + SELF_XLZ option) ============
template <bool SELF_XLZ>
__device__ void matvec_y(const Params& P, int mb, float* sm) {
    float* xs   = sm;          // 128
    float* xrow = sm + 128;    // 1024
    float* Wl   = sm + 1152;   // 1024
    float* zl   = sm + 2176;   // 128
    int t = threadIdx.x;
    for (int i = t; i < 1024; i += 256) Wl[i] = P.Wl[i];
    if (SELF_XLZ) {
        if (t < 128) zl[t] = P.z[t];
        __syncthreads();
        if (t < 128) {
            float s = P.lin_b[32 + t];
#pragma unroll 8
            for (int k = 0; k < 128; k++) s += zl[k] * P.lin_w[k * 160 + 32 + t];
            xs[t] = s;
        }
    } else {
        if (t < 128) xs[t] = (P.ws + O_XLZ)[t];
    }
    __syncthreads();
    size_t j0 = (size_t)mb * 1024 + t * 4;
    float4 acc = *(const float4*)(P.loc_b + j0);
#pragma unroll 8
    for (int k = 0; k < 128; k++) {
        float xk = xs[k];
        float4 w = *(const float4*)(P.loc_w + (size_t)k * LOCN + j0);
        acc.x += xk * w.x; acc.y += xk * w.y; acc.z += xk * w.z; acc.w += xk * w.w;
    }
    *(float4*)(xrow + t * 4) = acc;
    __syncthreads();
    float* yl0 = P.ws + O_YL0;
#pragma unroll
    for (int q = 0; q < 4; q++) {
        int idx = q * 256 + t;
        int nn = idx >> 5, f = idx & 31;
        float s = 0.f;
        const float* xr = xrow + nn * 32;
#pragma unroll
        for (int k = 0; k < 32; k++) s += xr[k] * Wl[k * 32 + f];
        yl0[(size_t)mb * 1024 + idx] = s;
    }
}

// ============ pull gather (F=32) + bias + BN stats (R10 body) ============
__device__ void gatherG(const int* rp, const int* ei, const float* y,
                        const float* bias, int n, float* xout, float* stats,
                        int rb, int nrb, float* sm) {
    int t = threadIdx.x, f = t & 31, half = (t >> 5) & 1, w = t >> 6;
    float bf = bias[f];
    float s = 0.f, ss = 0.f;
    for (int node = rb * 8 + w; node < n; node += nrb * 8) {
        int r0 = rp[node], r1 = rp[node + 1];
        float a = half ? 0.f : y[(size_t)node * 32 + f];
        for (int r = r0 + half; r < r1; r += 2)
            a += y[(size_t)ei[r] * 32 + f];
        a += __shfl_down(a, 32, 64);
        if (!half) {
            float v = a / (float)(r1 - r0 + 1) + bf;
            xout[(size_t)node * 32 + f] = v;
            s += v; ss += v * v;
        }
    }
    if (t < 64) sm[t] = 0.f;
    __syncthreads();
    if (!half) { atomicAdd(sm + f, s); atomicAdd(sm + 32 + f, ss); }
    __syncthreads();
    if (t < 64) atomicAdd(stats + t, sm[t]);
}

// ============ BN + leakyReLU + row @ W(32xFO), 512 threads (R10 body) ============
template <int FO>
__device__ void bnxw512(const float* xin, const float* stats, const float* gam,
                        const float* bet, const float* W, float invn, int n,
                        float* out, int rb, float* sm) {
    float* Wl = sm;
    float* sc = sm + 32 * FO;
    float* sh = sc + 32;
    int t = threadIdx.x;
    for (int i = t; i < 32 * FO; i += 512) Wl[i] = W[i];
    if (t < 32) {
        float mu = stats[t] * invn;
        float var = stats[32 + t] * invn - mu * mu;
        float rs = rsqrtf(var + 1e-5f);
        float scv = rs * gam[t];
        sc[t] = scv; sh[t] = bet[t] - mu * scv;
    }
    __syncthreads();
    int node = rb * 512 + t;
    if (node < n) {
        float x[32];
        const float4* xp = (const float4*)(xin + (size_t)node * 32);
#pragma unroll
        for (int j = 0; j < 8; j++) {
            float4 v = xp[j];
            x[4 * j] = v.x; x[4 * j + 1] = v.y; x[4 * j + 2] = v.z; x[4 * j + 3] = v.w;
        }
#pragma unroll
        for (int k = 0; k < 32; k++) {
            float v = sc[k] * x[k] + sh[k];
            x[k] = v > 0.f ? v : 0.01f * v;
        }
        float yv[FO];
#pragma unroll
        for (int q = 0; q < FO; q++) {
            float s = 0.f;
#pragma unroll
            for (int k = 0; k < 32; k++) s += x[k] * Wl[k * FO + q];
            yv[q] = s;
        }
        float* yp = out + (size_t)node * FO;
#pragma unroll
        for (int q = 0; q < FO; q++) yp[q] = yv[q];
    }
}

// ============ y = U(64 rows) @ xw(m x 32), 512 threads (R10 body) ============
__device__ void gemm512(const float* U, const float* xw, int m, float* y,
                        int rb, float* sm) {
    float* ut = sm;          // 64*64
    float* xt = sm + 4096;   // 64*32
    int t = threadIdx.x, f = t & 31, rg = t >> 5;
    int r0 = rb * 64;
    float a0 = 0, a1 = 0, a2 = 0, a3 = 0;
    for (int k0 = 0; k0 < m; k0 += 64) {
        {
            int row = t >> 3, c0 = (t & 7) * 8;
            const float* src = U + (size_t)(r0 + row) * m + k0 + c0;
            *(float4*)(ut + row * 64 + c0) = *(const float4*)src;
            *(float4*)(ut + row * 64 + c0 + 4) = *(const float4*)(src + 4);
        }
        {
            int kk = t >> 3, c0 = (t & 7) * 4;
            *(float4*)(xt + kk * 32 + c0) =
                *(const float4*)(xw + (size_t)(k0 + kk) * 32 + c0);
        }
        __syncthreads();
#pragma unroll
        for (int kk = 0; kk < 64; kk++) {
            float xv = xt[kk * 32 + f];
            a0 += ut[rg * 64 + kk] * xv;
            a1 += ut[(rg + 16) * 64 + kk] * xv;
            a2 += ut[(rg + 32) * 64 + kk] * xv;
            a3 += ut[(rg + 48) * 64 + kk] * xv;
        }
        __syncthreads();
    }
    y[(size_t)(r0 + rg) * 32 + f] = a0;
    y[(size_t)(r0 + rg + 16) * 32 + f] = a1;
    y[(size_t)(r0 + rg + 32) * 32 + f] = a2;
    y[(size_t)(r0 + rg + 48) * 32 + f] = a3;
}

// ================= K1: mv[0:191) self-xlz | hist | lin-head  (256) ============
__global__ void __launch_bounds__(256) k_l1(Params P) {
    __shared__ float sm[2304];
    int t = threadIdx.x, bid = blockIdx.x;
    float* ws = P.ws;
    if (bid < 191) {
        matvec_y<true>(P, bid, sm);
    } else if (bid < 255) {
        int* deg = (int*)(ws + O_DEG);
        for (int e = (bid - 191) * 256 + t; e < ETOT; e += 64 * 256) {
            const int* A; int E, dofs; int x = e;
            if (x < E0)              { A = P.A0; E = E0; dofs = 0; }
            else if ((x -= E0) < E1) { A = P.A1; E = E1; dofs = 16384; }
            else if ((x -= E1) < E2) { A = P.A2; E = E2; dofs = 20480; }
            else { x -= E2;            A = P.A3; E = E3; dofs = 21504; }
            atomicAdd(deg + dofs + A[E + x], 1);
        }
    } else {
        // lin head: xlz -> ws, xw0 broadcast -> ws
        float* zl  = sm;
        float* xl  = sm + 128;
        float* xw0 = sm + 288;
        if (t < 128) zl[t] = P.z[t];
        __syncthreads();
        if (t < 160) {
            float s = P.lin_b[t];
            for (int k = 0; k < 128; k++) s += zl[k] * P.lin_w[k * 160 + t];
            xl[t] = s;
        }
        __syncthreads();
        if (t < 128) (ws + O_XLZ)[t] = xl[32 + t];
        if (t < 32) {
            float s = 0.f;
            for (int k = 0; k < 32; k++) s += xl[k] * P.Wg[k * 32 + t];
            xw0[t] = s;
        }
        __syncthreads();
        for (int i = t; i < 2048; i += 256) (ws + O_XW0)[i] = xw0[i & 31];
    }
}

// ================= K2: scan | U3 gemm | mv[191:442)  (256) ============
__global__ void __launch_bounds__(256) k_l2(Params P) {
    __shared__ float sm[2304];
    int t = threadIdx.x, bid = blockIdx.x;
    float* ws = P.ws;
    if (bid < 4) {
        int n   = bid == 0 ? N0 : bid == 1 ? N1 : bid == 2 ? N2 : N3;
        int db  = bid == 0 ? 0 : bid == 1 ? 16384 : bid == 2 ? 20480 : 21504;
        int rbo = bid == 0 ? 0 : bid == 1 ? 16385 : bid == 2 ? 20482 : 21507;
        int per = n >> 8;
        const int* d = (int*)(ws + O_DEG) + db;
        int* rpp = (int*)(ws + O_RP) + rbo;
        int* cup = (int*)(ws + O_CUR) + rbo;
        int s = 0;
        for (int i = 0; i < per; i++) s += d[t * per + i];
        int* part = (int*)sm;
        part[t] = s;
        __syncthreads();
        for (int off = 1; off < 256; off <<= 1) {
            int v = (t >= off) ? part[t - off] : 0;
            __syncthreads();
            part[t] += v;
            __syncthreads();
        }
        int run = t ? part[t - 1] : 0;
        for (int i = 0; i < per; i++) {
            int idx = t * per + i;
            rpp[idx] = run; cup[idx] = run;
            run += d[idx];
        }
        if (t == 255) rpp[n] = part[255];
    } else if (bid == 4) {
        for (int i = t; i < 2048; i += 256) sm[i] = (ws + O_XW0)[i];
        __syncthreads();
        float acc[32];
#pragma unroll
        for (int f = 0; f < 32; f++) acc[f] = 0.f;
        for (int k = 0; k < 64; k++) {
            float u = P.U3[t * 64 + k];
#pragma unroll
            for (int f = 0; f < 32; f++) acc[f] += u * sm[k * 32 + f];
        }
        float* yp = ws + O_YG0 + t * 32;
#pragma unroll
        for (int f = 0; f < 32; f++) yp[f] = acc[f];
    } else {
        matvec_y<false>(P, 191 + (bid - 5), sm);
    }
}

// ================= K3: fill | mv[442:512)  (134) ============
__global__ void __launch_bounds__(256) k_l3(Params P) {
    __shared__ float sm[2304];
    int t = threadIdx.x, bid = blockIdx.x;
    float* ws = P.ws;
    if (bid < 64) {
        int* cur  = (int*)(ws + O_CUR);
        int* eidx = (int*)(ws + O_EIDX);
        for (int e = bid * 256 + t; e < ETOT; e += 64 * 256) {
            const int* A; int E, cofs, eofs; int x = e;
            if (x < E0)              { A = P.A0; E = E0; cofs = 0;     eofs = 0; }
            else if ((x -= E0) < E1) { A = P.A1; E = E1; cofs = 16385; eofs = 98304; }
            else if ((x -= E1) < E2) { A = P.A2; E = E2; cofs = 20482; eofs = 122880; }
            else { x -= E2;            A = P.A3; E = E3; cofs = 21507; eofs = 129024; }
            int srcn = A[x], dd = A[E + x];
            int slot = atomicAdd(cur + cofs + dd, 1);
            eidx[eofs + slot] = srcn;
        }
    } else {
        matvec_y<false>(P, 442 + (bid - 64), sm);
    }
}

// ================= K4: gather_l0 | gather_g0  (256 x 512) ============
__global__ void __launch_bounds__(512) k_l4(Params P) {
    __shared__ float sm[64];
    int bid = blockIdx.x;
    float* ws = P.ws;
    const int* rp = (int*)(ws + O_RP);
    const int* ei = (int*)(ws + O_EIDX);
    if (bid < 240)
        gatherG(rp, ei, ws + O_YL0, P.bl, N0, ws + O_XL1, ws + O_STAT + 192,
                bid, 240, sm);
    else
        gatherG(rp + 21507, ei + 129024, ws + O_YG0, P.bg, N3, ws + O_XG1,
                ws + O_STAT, bid - 240, 16, sm);
}

// ================= K5: bnxw_l0 | bnxw_g0  (33 x 512) ============
__global__ void __launch_bounds__(512) k_l5(Params P) {
    __shared__ float sm[1152];
    int bid = blockIdx.x;
    float* ws = P.ws;
    if (bid < 32)
        bnxw512<32>(ws + O_XL1, ws + O_STAT + 192, P.gam_l, P.bet_l, P.Wl + 1024,
                    1.f / N0, N0, ws + O_YL1, bid, sm);
    else
        bnxw512<32>(ws + O_XG1, ws + O_STAT, P.gam_g, P.bet_g, P.Wg + 1024,
                    1.f / N3, N3, ws + O_XWG1, bid - 32, sm);
}

// ================= K6: gather_l1 | gemmU2  (256 x 512) ============
__global__ void __launch_bounds__(512) k_l6(Params P) {
    __shared__ float sm[6144];
    int bid = blockIdx.x;
    float* ws = P.ws;
    const int* rp = (int*)(ws + O_RP);
    const int* ei = (int*)(ws + O_EIDX);
    if (bid < 240)
        gatherG(rp, ei, ws + O_YL1, P.bl + 32, N0, ws + O_XL2,
                ws + O_STAT + 256, bid, 240, sm);
    else
        gemm512(P.U2, ws + O_XWG1, 256, ws + O_YG1, bid - 240, sm);
}

// ================= K7: bnxw_l1 | gather_g1  (48 x 512) ============
__global__ void __launch_bounds__(512) k_l7(Params P) {
    __shared__ float sm[1152];
    int bid = blockIdx.x;
    float* ws = P.ws;
    const int* rp = (int*)(ws + O_RP);
    const int* ei = (int*)(ws + O_EIDX);
    if (bid < 32)
        bnxw512<32>(ws + O_XL2, ws + O_STAT + 256, P.gam_l + 32, P.bet_l + 32,
                    P.Wl + 2048, 1.f / N0, N0, ws + O_YL2, bid, sm);
    else
        gatherG(rp + 20482, ei + 122880, ws + O_YG1, P.bg + 32, N2,
                ws + O_XG2, ws + O_STAT + 64, bid - 32, 16, sm);
}

// ================= K8: gather_l2 | bnxw_g1  (242 x 512) ============
__global__ void __launch_bounds__(512) k_l8(Params P) {
    __shared__ float sm[1152];
    int bid = blockIdx.x;
    float* ws = P.ws;
    const int* rp = (int*)(ws + O_RP);
    const int* ei = (int*)(ws + O_EIDX);
    if (bid < 240)
        gatherG(rp, ei, ws + O_YL2, P.bl + 64, N0, ws + O_XL3,
                ws + O_STAT + 320, bid, 240, sm);
    else
        bnxw512<32>(ws + O_XG2, ws + O_STAT + 64, P.gam_g + 32, P.bet_g + 32,
                    P.Wg + 2048, 1.f / N2, N2, ws + O_XWG2, bid - 240, sm);
}

// ================= K9: bnxw_l2 (FO=3) | gemmU1  (96 x 512) ============
__global__ void __launch_bounds__(512) k_l9(Params P) {
    __shared__ float sm[6144];
    int bid = blockIdx.x;
    float* ws = P.ws;
    if (bid < 32)
        bnxw512<3>(ws + O_XL3, ws + O_STAT + 320, P.gam_l + 64, P.bet_l + 64,
                   P.Wl3, 1.f / N0, N0, ws + O_YL3, bid, sm);
    else
        gemm512(P.U1, ws + O_XWG2, 1024, ws + O_YG2, bid - 32, sm);
}

// ================= K10: gather_g2  (64 x 512) ============
__global__ void __launch_bounds__(512) k_l10(Params P) {
    __shared__ float sm[64];
    float* ws = P.ws;
    const int* rp = (int*)(ws + O_RP);
    const int* ei = (int*)(ws + O_EIDX);
    gatherG(rp + 16385, ei + 98304, ws + O_YG2, P.bg + 64, N1,
            ws + O_XG3, ws + O_STAT + 128, blockIdx.x, 64, sm);
}

// ================= K11: bnxw_g2 (FO=3)  (8 x 512) ============
__global__ void __launch_bounds__(512) k_l11(Params P) {
    __shared__ float sm[256];
    bnxw512<3>(P.ws + O_XG3, P.ws + O_STAT + 128, P.gam_g + 64, P.bet_g + 64,
               P.Wg3, 1.f / N1, N1, P.ws + O_XW3, blockIdx.x, sm);
}

// ================= K12: yg3 = U0 @ xw3  (256 x 256) ============
__global__ void __launch_bounds__(256) k_gemmU3(Params P) {
    __shared__ float pl[12288];
    int t = threadIdx.x;
    const float* xw3 = P.ws + O_XW3;
    float* y = P.ws + O_YG3;
    for (int i = t; i < 12288; i += 256) {
        int k = i / 3, h = i - 3 * k;
        pl[h * 4096 + ((k & 3) << 10) + (k >> 2)] = xw3[i];
    }
    __syncthreads();
    int w = t >> 6, lane = t & 63;
    for (int it = 0; it < 4; it++) {
        for (int rr = 0; rr < 4; rr++) {
            int row = it * 4096 + blockIdx.x * 16 + w * 4 + rr;
            const float4* up = (const float4*)(P.U0 + (size_t)row * 4096);
            float a0 = 0, a1 = 0, a2 = 0;
#pragma unroll 4
            for (int c = 0; c < 16; c++) {
                float4 u = up[c * 64 + lane];
                int b = c * 64 + lane;
                a0 += u.x * pl[b]        + u.y * pl[1024 + b]  + u.z * pl[2048 + b]   + u.w * pl[3072 + b];
                a1 += u.x * pl[4096 + b] + u.y * pl[5120 + b]  + u.z * pl[6144 + b]   + u.w * pl[7168 + b];
                a2 += u.x * pl[8192 + b] + u.y * pl[9216 + b]  + u.z * pl[10240 + b]  + u.w * pl[11264 + b];
            }
            for (int o = 32; o; o >>= 1) {
                a0 += __shfl_down(a0, o, 64);
                a1 += __shfl_down(a1, o, 64);
                a2 += __shfl_down(a2, o, 64);
            }
            if (lane == 0) { y[row * 3] = a0; y[row * 3 + 1] = a1; y[row * 3 + 2] = a2; }
        }
    }
}

// ================= K13: final combine over A0  (256 x 256) ============
__global__ void __launch_bounds__(256) k_final(Params P) {
    int t = blockIdx.x * 256 + threadIdx.x;
    int node = t >> 2, r = t & 3;
    if (node >= N0 || r >= 3) return;
    float* ws = P.ws;
    const int* rp = (int*)(ws + O_RP);
    const int* ei = (int*)(ws + O_EIDX);
    const float* yg = ws + O_YG3;
    const float* yl = ws + O_YL3;
    int r0 = rp[node], r1 = rp[node + 1];
    float ag = yg[node * 3 + r], al = yl[node * 3 + r];
    int e = r0;
    for (; e + 4 <= r1; e += 4) {
        int s0 = ei[e], s1 = ei[e + 1], s2 = ei[e + 2], s3 = ei[e + 3];
        ag += yg[s0 * 3 + r] + yg[s1 * 3 + r] + yg[s2 * 3 + r] + yg[s3 * 3 + r];
        al += yl[s0 * 3 + r] + yl[s1 * 3 + r] + yl[s2 * 3 + r] + yl[s3 * 3 + r];
    }
    for (; e < r1; e++) { ag += yg[ei[e] * 3 + r]; al += yl[ei[e] * 3 + r]; }
    float inv = 1.f / (float)(r1 - r0 + 1);
    P.out[node * 3 + r] = 0.01f * (ag * inv + P.bg3[r]) + 0.99f * (al * inv + P.bl3[r]);
}

extern "C" void kernel_launch(void* const* d_in, const int* in_sizes, int n_in,
                              void* d_out, int out_size, void* d_ws, size_t ws_size,
                              hipStream_t stream) {
    Params p;
    p.z     = (const float*)d_in[0];
    p.lin_w = (const float*)d_in[1];
    p.lin_b = (const float*)d_in[2];
    p.loc_w = (const float*)d_in[3];
    p.loc_b = (const float*)d_in[4];
    p.Wg    = (const float*)d_in[5];
    p.bg    = (const float*)d_in[8];
    p.Wg3   = (const float*)d_in[9];
    p.bg3   = (const float*)d_in[12];
    p.Wl    = (const float*)d_in[13];
    p.bl    = (const float*)d_in[16];
    p.Wl3   = (const float*)d_in[17];
    p.bl3   = (const float*)d_in[20];
    p.gam_g = (const float*)d_in[21];
    p.bet_g = (const float*)d_in[22];
    p.gam_l = (const float*)d_in[23];
    p.bet_l = (const float*)d_in[24];
    p.U0    = (const float*)d_in[25];
    p.U1    = (const float*)d_in[26];
    p.U2    = (const float*)d_in[27];
    p.U3    = (const float*)d_in[28];
    p.A0    = (const int*)d_in[29];
    p.A1    = (const int*)d_in[30];
    p.A2    = (const int*)d_in[31];
    p.A3    = (const int*)d_in[32];
    p.ws    = (float*)d_ws;
    p.out   = (float*)d_out;

    hipMemsetAsync(d_ws, 0, (21760 + 384) * 4, stream);  // deg + stats
    k_l1    <<<256, 256, 0, stream>>>(p);  // mv 0:191 | hist | lin-head
    k_l2    <<<256, 256, 0, stream>>>(p);  // scan | U3 gemm | mv 191:442
    k_l3    <<<134, 256, 0, stream>>>(p);  // fill | mv 442:512
    k_l4    <<<256, 512, 0, stream>>>(p);  // gather_l0 | gather_g0
    k_l5    <<<33,  512, 0, stream>>>(p);  // bnxw_l0 | bnxw_g0
    k_l6    <<<256, 512, 0, stream>>>(p);  // gather_l1 | gemmU2
    k_l7    <<<48,  512, 0, stream>>>(p);  // bnxw_l1 | gather_g1
    k_l8    <<<242, 512, 0, stream>>>(p);  // gather_l2 | bnxw_g1
    k_l9    <<<96,  512, 0, stream>>>(p);  // bnxw_l2 | gemmU1
    k_l10   <<<64,  512, 0, stream>>>(p);  // gather_g2
    k_l11   <<<8,   512, 0, stream>>>(p);  // bnxw_g2
    k_gemmU3<<<256, 256, 0, stream>>>(p);  // U0 @ xw3
    k_final <<<256, 256, 0, stream>>>(p);  // combine
}